// Round 1
// baseline (347.157 us; speedup 1.0000x reference)
//
#include <hip/hip_runtime.h>
#include <hip/hip_bf16.h>

#define HW 131072      // h*w
#define NCH 128        // channels
#define KS 9
#define L_TOTAL 163840 // Q*M*M
#define LPW 16         // l's per wave in main kernel

typedef float        f32x2 __attribute__((ext_vector_type(2)));
typedef float        f32x4 __attribute__((ext_vector_type(4)));

static __device__ __forceinline__ float bflo(unsigned int p) { return __uint_as_float(p << 16); }
static __device__ __forceinline__ float bfhi(unsigned int p) { return __uint_as_float(p & 0xffff0000u); }
static __device__ __forceinline__ unsigned short f2bf(float f) {
    unsigned int x = __float_as_uint(f);
    return (unsigned short)((x + 0x7fffu + ((x >> 16) & 1u)) >> 16);  // RNE
}
static __device__ __forceinline__ unsigned int pack2(float a, float b) {
    return (unsigned int)f2bf(a) | ((unsigned int)f2bf(b) << 16);
}

// ---------------------------------------------------------------------------
// Kernel A: transpose x[c][p] (fp32) -> xT[p][c] (bf16 pairs) AND per-p
// channel mean/max. x read nt (read-once).  (unchanged)
// ---------------------------------------------------------------------------
__global__ __launch_bounds__(256) void transpose_x_kernel(
    const f32x2* __restrict__ xf,         // x: [NCH][HW/2] float2 along p
    unsigned int* __restrict__ xT,        // [HW][NCH/2] uint pairs along c
    float2* __restrict__ meanmaxP)        // [HW] (mean, max) over channels
{
    __shared__ unsigned short tile[128 * 128];  // [p][col'], rotate swizzle
    __shared__ float ps[4][128];
    __shared__ float pm[4][128];
    const int tid = threadIdx.x;
    const int lane = tid & 63;
    const int wave = tid >> 6;
    const int p0 = blockIdx.x * 128;
    const int pa = 2 * lane, pb = 2 * lane + 1;

    float s0 = 0.f, s1 = 0.f;
    float m0 = -3.4e38f, m1 = -3.4e38f;
    #pragma unroll 8
    for (int it = 0; it < 32; ++it) {
        int c = wave + (it << 2);
        f32x2 v = __builtin_nontemporal_load(&xf[(long)c * (HW / 2) + (p0 >> 1) + lane]);
        tile[pa * 128 + ((c + 2 * pa) & 127)] = f2bf(v.x);
        tile[pb * 128 + ((c + 2 * pb) & 127)] = f2bf(v.y);
        s0 += v.x; s1 += v.y;
        m0 = fmaxf(m0, v.x); m1 = fmaxf(m1, v.y);
    }
    ps[wave][pa] = s0; ps[wave][pb] = s1;
    pm[wave][pa] = m0; pm[wave][pb] = m1;
    __syncthreads();

    #pragma unroll 8
    for (int it = 0; it < 32; ++it) {
        int p = wave + (it << 2);
        int colr = (2 * lane + 2 * p) & 127;          // even -> dword aligned
        unsigned int d = *reinterpret_cast<const unsigned int*>(&tile[p * 128 + colr]);
        xT[(long)(p0 + p) * 64 + lane] = d;
    }
    if (tid < 128) {
        float s = ps[0][tid] + ps[1][tid] + ps[2][tid] + ps[3][tid];
        float m = fmaxf(fmaxf(pm[0][tid], pm[1][tid]), fmaxf(pm[2][tid], pm[3][tid]));
        meanmaxP[p0 + tid] = make_float2(s * 0.0078125f, m);
    }
}

// ---------------------------------------------------------------------------
// Kernel B: fused gather + attention + depthwise.
// NEW: depth-3 software-pipelined gather. Indices come from LDS (in-order DS
// completion -> fine-grained lgkmcnt, unlike SMEM's lgkmcnt(0) drain).
// Per-lane voffset addressing: base + (idx<<8) + lane*4. 3 pv buffers so two
// iterations of gathers (18 loads) stay in flight while one is consumed.
// Prologue issues 27 gathers BEFORE the phase-1 barrier.
// nt stores on ybuf keep the 46 MB write stream from evicting xT in L2.
// Grid: L_TOTAL/64 = 2560 blocks, 256 threads.
// ---------------------------------------------------------------------------
#define GLD(IDX) (*(const unsigned int*)(xTc + (((unsigned)(IDX)) << 8) + (unsigned)lane4))
#define ISSUE9(B, A0, A1, A8)            \
    pv[B][0] = GLD((A0).x);              \
    pv[B][1] = GLD((A0).y);              \
    pv[B][2] = GLD((A0).z);              \
    pv[B][3] = GLD((A0).w);              \
    pv[B][4] = GLD((A1).x);              \
    pv[B][5] = GLD((A1).y);              \
    pv[B][6] = GLD((A1).z);              \
    pv[B][7] = GLD((A1).w);              \
    pv[B][8] = GLD(A8)

__global__ __launch_bounds__(256, 5) void encoder_main_kernel(
    const unsigned int* __restrict__ xT,       // [HW][64]
    const float2* __restrict__ meanmaxP,       // [HW]
    const int* __restrict__ cks,               // [L][9]
    const float* __restrict__ att_w,           // [9][2][9]
    const float* __restrict__ att_b,           // [9]
    const float* __restrict__ depth_w,         // [128][9]
    const float* __restrict__ depth_b,         // [128]
    unsigned int* __restrict__ ybuf,           // [L][64] bf16 pairs
    float* __restrict__ gsum, float* __restrict__ gsq)
{
    __shared__ __align__(16) char smem[6832];
    float* attw   = (float*)smem;                 // 162 f  [0, 648)
    float* attb   = (float*)(smem + 648);         // 9 f    [648, 684) pad->688
    int*   lcks   = (int*)(smem + 688);           // 64*12 i [688, 3760) stride-12, 16B-aligned rows
    float* mult12 = (float*)(smem + 3760);        // 64*12 f [3760, 6832)
    float* red    = (float*)smem;                 // 4096 B aliased (dead later)

    const int tid = threadIdx.x;
    const int lane = tid & 63;
    const int wave = tid >> 6;
    const int c0 = lane * 2, c1 = c0 + 1;
    const int base_l = blockIdx.x * 64;
    const int lane4 = lane << 2;
    const char* xTc = (const char*)xT;

    if (tid < 162) attw[tid] = att_w[tid];
    if (tid < KS) attb[tid] = att_b[tid];
    for (int j = tid; j < 64 * KS; j += 256) {
        const int lj = j / KS;
        lcks[lj * 12 + (j - lj * KS)] = __builtin_nontemporal_load(&cks[base_l * KS + j]);
    }

    float dw0[KS], dw1[KS];
    #pragma unroll
    for (int k = 0; k < KS; ++k) {
        dw0[k] = depth_w[c0 * KS + k];
        dw1[k] = depth_w[c1 * KS + k];
    }
    const float db0 = depth_b[c0], db1 = depth_b[c1];
    __syncthreads();

    // ---- Phase 1: multipliers. thread -> (l_local = tid>>2, sub = tid&3) ----
    {
        const int l_local = tid >> 2;
        const int sub = tid & 3;
        if (sub < 3) {
            float mean[KS], mx[KS];
            #pragma unroll
            for (int k = 0; k < KS; ++k) {
                float2 mm = meanmaxP[lcks[l_local * 12 + k]];
                mean[k] = mm.x; mx[k] = mm.y;
            }
            #pragma unroll
            for (int oo = 0; oo < 3; ++oo) {
                int o = sub * 3 + oo;
                float logit = attb[o];
                #pragma unroll
                for (int k = 0; k < KS; ++k) {
                    logit = fmaf(mean[k], attw[o * 18 + k], logit);
                    logit = fmaf(mx[k],   attw[o * 18 + 9 + k], logit);
                }
                mult12[l_local * 12 + o] = 1.0f + 1.0f / (1.0f + __expf(-logit));
            }
        }
    }

    // ---- Pipeline prologue: issue gathers for li=0..2 BEFORE the barrier,
    // so they are in flight while waves wait on __syncthreads. lcks is
    // already valid (written before the first barrier).
    const int ll0 = wave * LPW;
    unsigned int pv[3][KS];

    #pragma unroll
    for (int li = 0; li < 3; ++li) {
        const int p = (ll0 + li) * 12;
        const int4 i0 = *(const int4*)&lcks[p];
        const int4 i1 = *(const int4*)&lcks[p + 4];
        const int  i8 = lcks[p + 8];
        ISSUE9(li, i0, i1, i8);
    }

    __syncthreads();   // mult12 ready

    // ---- Phase 2: depth-3 pipelined gather + depthwise ----
    float sum0 = 0.f, sum1 = 0.f, sq0 = 0.f, sq1 = 0.f;

    #pragma unroll
    for (int li = 0; li < LPW; ++li) {
        // A) ds_read indices for li+3 (in-order DS -> no lgkmcnt(0) drain)
        int4 ni0 = make_int4(0, 0, 0, 0), ni1 = make_int4(0, 0, 0, 0);
        int ni8 = 0;
        if (li + 3 < LPW) {
            const int p = (ll0 + li + 3) * 12;
            ni0 = *(const int4*)&lcks[p];
            ni1 = *(const int4*)&lcks[p + 4];
            ni8 = lcks[p + 8];
        }

        // B) consume pv[li%3]  (waits vmcnt leaving li+1, li+2 in flight)
        const int ll = ll0 + li;
        const f32x4 mA = *(const f32x4*)&mult12[ll * 12 + 0];
        const f32x4 mB = *(const f32x4*)&mult12[ll * 12 + 4];
        const float m8 = mult12[ll * 12 + 8];
        float acc0 = db0, acc1 = db1;

        acc0 = fmaf(bflo(pv[li % 3][0]) * mA.x, dw0[0], acc0);
        acc1 = fmaf(bfhi(pv[li % 3][0]) * mA.x, dw1[0], acc1);
        acc0 = fmaf(bflo(pv[li % 3][1]) * mA.y, dw0[1], acc0);
        acc1 = fmaf(bfhi(pv[li % 3][1]) * mA.y, dw1[1], acc1);
        acc0 = fmaf(bflo(pv[li % 3][2]) * mA.z, dw0[2], acc0);
        acc1 = fmaf(bfhi(pv[li % 3][2]) * mA.z, dw1[2], acc1);
        acc0 = fmaf(bflo(pv[li % 3][3]) * mA.w, dw0[3], acc0);
        acc1 = fmaf(bfhi(pv[li % 3][3]) * mA.w, dw1[3], acc1);
        acc0 = fmaf(bflo(pv[li % 3][4]) * mB.x, dw0[4], acc0);
        acc1 = fmaf(bfhi(pv[li % 3][4]) * mB.x, dw1[4], acc1);
        acc0 = fmaf(bflo(pv[li % 3][5]) * mB.y, dw0[5], acc0);
        acc1 = fmaf(bfhi(pv[li % 3][5]) * mB.y, dw1[5], acc1);
        acc0 = fmaf(bflo(pv[li % 3][6]) * mB.z, dw0[6], acc0);
        acc1 = fmaf(bfhi(pv[li % 3][6]) * mB.z, dw1[6], acc1);
        acc0 = fmaf(bflo(pv[li % 3][7]) * mB.w, dw0[7], acc0);
        acc1 = fmaf(bfhi(pv[li % 3][7]) * mB.w, dw1[7], acc1);
        acc0 = fmaf(bflo(pv[li % 3][8]) * m8,   dw0[8], acc0);
        acc1 = fmaf(bfhi(pv[li % 3][8]) * m8,   dw1[8], acc1);

        __builtin_nontemporal_store(pack2(acc0, acc1),
                                    &ybuf[(long)(base_l + ll) * 64 + lane]);
        sum0 += acc0; sum1 += acc1;
        sq0 = fmaf(acc0, acc0, sq0);
        sq1 = fmaf(acc1, acc1, sq1);

        // C) refill buffer with gathers for li+3
        if (li + 3 < LPW) {
            ISSUE9(li % 3, ni0, ni1, ni8);
        }
    }

    __syncthreads();                 // smem front section dead now
    red[0 * 256 + tid] = sum0;
    red[1 * 256 + tid] = sum1;
    red[2 * 256 + tid] = sq0;
    red[3 * 256 + tid] = sq1;
    __syncthreads();

    const int grp = tid >> 6;
    const int i = tid & 63;
    float t = red[grp * 256 + i] + red[grp * 256 + 64 + i] +
              red[grp * 256 + 128 + i] + red[grp * 256 + 192 + i];
    float* dst = (grp & 2) ? gsq : gsum;
    atomicAdd(&dst[2 * i + (grp & 1)], t);
}

// ---------------------------------------------------------------------------
// Kernel C: BN finalize + SiLU + transpose ybuf[l][c] (bf16) -> out[q][c][r]
// (fp32) via LDS tile [c][r].  (unchanged)
// Grid: Q*(M*M/128) = 1280 blocks, 256 threads.
// ---------------------------------------------------------------------------
__global__ __launch_bounds__(256) void finalize_kernel(
    const unsigned int* __restrict__ ybuf,     // [L][64]
    const float* __restrict__ gsum, const float* __restrict__ gsq,
    const float* __restrict__ gamma, const float* __restrict__ beta,
    float* __restrict__ out)                   // [Q*NCH][16384]
{
    __shared__ unsigned short tile[128 * 130];  // [c][r], stride 130
    const int tid = threadIdx.x;
    const int lane = tid & 63;
    const int wave = tid >> 6;
    const int q = blockIdx.x >> 7;
    const int r0 = (blockIdx.x & 127) * 128;
    const int c0 = 2 * lane, c1 = c0 + 1;

    const long lbase = (long)q * 16384 + r0;
    #pragma unroll 8
    for (int it = 0; it < 32; ++it) {
        int r = wave + (it << 2);
        unsigned int u = __builtin_nontemporal_load(&ybuf[(lbase + r) * 64 + lane]);
        tile[c0 * 130 + r] = (unsigned short)(u & 0xffffu);
        tile[c1 * 130 + r] = (unsigned short)(u >> 16);
    }
    __syncthreads();

    const float invN = 1.0f / (float)L_TOTAL;
    #pragma unroll 4
    for (int it = 0; it < 32; ++it) {
        int c = wave + (it << 2);
        float m = gsum[c] * invN;
        float var = gsq[c] * invN - m * m;
        float sc = gamma[c] * rsqrtf(var + 1e-5f);
        float sh = beta[c] - m * sc;
        unsigned int d = *reinterpret_cast<const unsigned int*>(&tile[c * 130 + 2 * lane]);
        float z0 = fmaf(bflo(d), sc, sh);
        float z1 = fmaf(bfhi(d), sc, sh);
        f32x2 v;
        v.x = z0 / (1.0f + __expf(-z0));
        v.y = z1 / (1.0f + __expf(-z1));
        *(f32x2*)&out[((long)(q * NCH + c) << 14) + r0 + 2 * lane] = v;
    }
}

extern "C" void kernel_launch(void* const* d_in, const int* in_sizes, int n_in,
                              void* d_out, int out_size, void* d_ws, size_t ws_size,
                              hipStream_t stream) {
    const f32x2* x_f2  = (const f32x2*)d_in[0];
    const int* cks     = (const int*)d_in[1];
    const float* aw    = (const float*)d_in[2];
    const float* ab    = (const float*)d_in[3];
    const float* dw    = (const float*)d_in[4];
    const float* db    = (const float*)d_in[5];
    const float* gm    = (const float*)d_in[6];
    const float* bt    = (const float*)d_in[7];

    char* ws = (char*)d_ws;
    unsigned int* xT   = (unsigned int*)ws;                  // 33,554,432 B
    float2* meanmaxP   = (float2*)(ws + 33554432);           // 1,048,576 B
    unsigned int* ybuf = (unsigned int*)(ws + 34603008);     // 41,943,040 B
    float* gsum        = (float*)(ws + 34603008 + 41943040); // 512 B
    float* gsq         = gsum + NCH;                         // 512 B

    hipMemsetAsync(gsum, 0, 2 * NCH * sizeof(float), stream);

    transpose_x_kernel<<<HW / 128, 256, 0, stream>>>(x_f2, xT, meanmaxP);
    encoder_main_kernel<<<L_TOTAL / 64, 256, 0, stream>>>(
        xT, meanmaxP, cks, aw, ab, dw, db, ybuf, gsum, gsq);
    finalize_kernel<<<1280, 256, 0, stream>>>(
        ybuf, gsum, gsq, gm, bt, (float*)d_out);
}

// Round 2
// 303.414 us; speedup vs baseline: 1.1442x; 1.1442x over previous
//
#include <hip/hip_runtime.h>
#include <hip/hip_bf16.h>

#define HW 131072      // h*w
#define NCH 128        // channels
#define KS 9
#define L_TOTAL 163840 // Q*M*M
#define NGRP 8         // channel groups == XCDs
#define LPB 128        // l's per block in gather kernel

typedef float        f32x2 __attribute__((ext_vector_type(2)));
typedef float        f32x4 __attribute__((ext_vector_type(4)));

static __device__ __forceinline__ float bflo(unsigned int p) { return __uint_as_float(p << 16); }
static __device__ __forceinline__ float bfhi(unsigned int p) { return __uint_as_float(p & 0xffff0000u); }
static __device__ __forceinline__ unsigned short f2bf(float f) {
    unsigned int x = __float_as_uint(f);
    return (unsigned short)((x + 0x7fffu + ((x >> 16) & 1u)) >> 16);  // RNE
}
static __device__ __forceinline__ unsigned int pack2(float a, float b) {
    return (unsigned int)f2bf(a) | ((unsigned int)f2bf(b) << 16);
}

// ---------------------------------------------------------------------------
// Kernel A: transpose x[c][p] (fp32) -> xT slabs: [g][p][8 dwords] where
// slab g holds channels [16g, 16g+16) as bf16 pairs (32 B per row = 4 MB
// per slab = one XCD L2). Also per-p channel mean/max.
// Grid: HW/128 = 1024 blocks, 256 threads.
// ---------------------------------------------------------------------------
__global__ __launch_bounds__(256) void transpose_x_kernel(
    const f32x2* __restrict__ xf,         // x: [NCH][HW/2] float2 along p
    unsigned int* __restrict__ xT,        // [8][HW][8] dword slabs
    float2* __restrict__ meanmaxP)        // [HW] (mean, max) over channels
{
    __shared__ unsigned short tile[128 * 128];  // [p][col'], rotate swizzle
    __shared__ float ps[4][128];
    __shared__ float pm[4][128];
    const int tid = threadIdx.x;
    const int lane = tid & 63;
    const int wave = tid >> 6;
    const int p0 = blockIdx.x * 128;
    const int pa = 2 * lane, pb = 2 * lane + 1;

    float s0 = 0.f, s1 = 0.f;
    float m0 = -3.4e38f, m1 = -3.4e38f;
    #pragma unroll 8
    for (int it = 0; it < 32; ++it) {
        int c = wave + (it << 2);
        f32x2 v = __builtin_nontemporal_load(&xf[(long)c * (HW / 2) + (p0 >> 1) + lane]);
        tile[pa * 128 + ((c + 2 * pa) & 127)] = f2bf(v.x);
        tile[pb * 128 + ((c + 2 * pb) & 127)] = f2bf(v.y);
        s0 += v.x; s1 += v.y;
        m0 = fmaxf(m0, v.x); m1 = fmaxf(m1, v.y);
    }
    ps[wave][pa] = s0; ps[wave][pb] = s1;
    pm[wave][pa] = m0; pm[wave][pb] = m1;
    __syncthreads();

    #pragma unroll 8
    for (int it = 0; it < 32; ++it) {
        int p = wave + (it << 2);
        int colr = (2 * lane + 2 * p) & 127;          // even -> dword aligned
        unsigned int d = *reinterpret_cast<const unsigned int*>(&tile[p * 128 + colr]);
        // dword holds channels (2*lane, 2*lane+1) -> slab lane>>3, sub lane&7
        xT[((long)(lane >> 3) * HW + (p0 + p)) * 8 + (lane & 7)] = d;
    }
    if (tid < 128) {
        float s = ps[0][tid] + ps[1][tid] + ps[2][tid] + ps[3][tid];
        float m = fmaxf(fmaxf(pm[0][tid], pm[1][tid]), fmaxf(pm[2][tid], pm[3][tid]));
        meanmaxP[p0 + tid] = make_float2(s * 0.0078125f, m);
    }
}

// ---------------------------------------------------------------------------
// Kernel B1: attention multipliers, hoisted out so the XCD-sliced gather
// kernel doesn't duplicate it 8x. mult[l][o] = 1 + sigmoid(logit).
// Grid: L_TOTAL/64 = 2560 blocks, 256 threads.
// ---------------------------------------------------------------------------
__global__ __launch_bounds__(256) void mult_kernel(
    const float2* __restrict__ meanmaxP,       // [HW]
    const int* __restrict__ cks,               // [L][9]
    const float* __restrict__ att_w,           // [9][2][9]
    const float* __restrict__ att_b,           // [9]
    float* __restrict__ multg)                 // [L][12] (0..8 used)
{
    __shared__ float attw[162];
    __shared__ float attb[12];
    __shared__ int lcks[64 * 12];
    const int tid = threadIdx.x;
    const int base_l = blockIdx.x * 64;

    if (tid < 162) attw[tid] = att_w[tid];
    if (tid < KS) attb[tid] = att_b[tid];
    for (int j = tid; j < 64 * KS; j += 256) {
        const int lj = j / KS;
        lcks[lj * 12 + (j - lj * KS)] = cks[(long)base_l * KS + j];
    }
    __syncthreads();

    const int l_local = tid >> 2;
    const int sub = tid & 3;
    if (sub < 3) {
        float mean[KS], mx[KS];
        #pragma unroll
        for (int k = 0; k < KS; ++k) {
            float2 mm = meanmaxP[lcks[l_local * 12 + k]];
            mean[k] = mm.x; mx[k] = mm.y;
        }
        #pragma unroll
        for (int oo = 0; oo < 3; ++oo) {
            int o = sub * 3 + oo;
            float logit = attb[o];
            #pragma unroll
            for (int k = 0; k < KS; ++k) {
                logit = fmaf(mean[k], attw[o * 18 + k], logit);
                logit = fmaf(mx[k],   attw[o * 18 + 9 + k], logit);
            }
            multg[(long)(base_l + l_local) * 12 + o] = 1.0f + 1.0f / (1.0f + __expf(-logit));
        }
    }
}

// ---------------------------------------------------------------------------
// Kernel B2: XCD-sliced gather + depthwise. g = blockIdx & 7 selects the
// 16-channel group AND (via HW round-robin dispatch) the XCD, so every
// gather hits that XCD's L2-resident 4 MB slab. Streaming inputs (cks,
// mult) use nt loads to avoid evicting the slab. Plain ybuf stores
// (nt stores = 3x write amplification, measured round 1).
// Grid: (L_TOTAL/LPB)*8 = 10240 blocks, 256 threads.
// ---------------------------------------------------------------------------
__global__ __launch_bounds__(256, 6) void gather_kernel(
    const unsigned int* __restrict__ xT,       // [8][HW][8]
    const int* __restrict__ cks,               // [L][9]
    const float* __restrict__ multg,           // [L][12]
    const float* __restrict__ depth_w,         // [128][9]
    const float* __restrict__ depth_b,         // [128]
    unsigned int* __restrict__ ybuf,           // [8][L][8] bf16-pair slabs
    float* __restrict__ gsum, float* __restrict__ gsq)
{
    __shared__ __align__(16) char smem[12288];
    int*   lcks = (int*)smem;                  // [0, 6144)  LPB rows stride 12
    float* mult = (float*)(smem + 6144);       // [6144, 12288) LPB rows stride 12
    float* red  = (float*)smem;                // aliased after phase 2

    const int tid  = threadIdx.x;
    const int lane = tid & 63;
    const int wave = tid >> 6;
    const int g      = blockIdx.x & 7;
    const int base_l = (blockIdx.x >> 3) * LPB;
    const int d    = lane & 7;   // dword within 32B row
    const int lsub = lane >> 3;  // which l in the octet

    for (int j = tid; j < LPB * KS; j += 256) {
        const int lj = j / KS;
        lcks[lj * 12 + (j - lj * KS)] = __builtin_nontemporal_load(&cks[(long)base_l * KS + j]);
    }
    for (int j = tid; j < LPB * 12; j += 256)
        mult[j] = __builtin_nontemporal_load(&multg[(long)base_l * 12 + j]);

    const int c0 = g * 16 + 2 * d, c1 = c0 + 1;
    float dw0[KS], dw1[KS];
    #pragma unroll
    for (int k = 0; k < KS; ++k) {
        dw0[k] = depth_w[c0 * KS + k];
        dw1[k] = depth_w[c1 * KS + k];
    }
    const float db0 = depth_b[c0], db1 = depth_b[c1];

    const unsigned int* slab  = xT   + (long)g * HW * 8;
    unsigned int*       yslab = ybuf + (long)g * L_TOTAL * 8;
    __syncthreads();

    float sum0 = 0.f, sum1 = 0.f, sq0 = 0.f, sq1 = 0.f;
    const int l0 = wave * (LPB / 4);           // 32 l's per wave

    #pragma unroll
    for (int oct = 0; oct < LPB / 32; ++oct) { // 4 octets of 8 l's
        const int l = l0 + oct * 8 + lsub;     // this lane's l (local)
        const int4 i0 = *(const int4*)&lcks[l * 12];
        const int4 i1 = *(const int4*)&lcks[l * 12 + 4];
        const int  i8 = lcks[l * 12 + 8];

        unsigned int pv0 = slab[(long)(unsigned)i0.x * 8 + d];
        unsigned int pv1 = slab[(long)(unsigned)i0.y * 8 + d];
        unsigned int pv2 = slab[(long)(unsigned)i0.z * 8 + d];
        unsigned int pv3 = slab[(long)(unsigned)i0.w * 8 + d];
        unsigned int pv4 = slab[(long)(unsigned)i1.x * 8 + d];
        unsigned int pv5 = slab[(long)(unsigned)i1.y * 8 + d];
        unsigned int pv6 = slab[(long)(unsigned)i1.z * 8 + d];
        unsigned int pv7 = slab[(long)(unsigned)i1.w * 8 + d];
        unsigned int pv8 = slab[(long)(unsigned)i8   * 8 + d];

        const f32x4 mA = *(const f32x4*)&mult[l * 12];
        const f32x4 mB = *(const f32x4*)&mult[l * 12 + 4];
        const float m8 = mult[l * 12 + 8];

        float acc0 = db0, acc1 = db1;
        acc0 = fmaf(bflo(pv0) * mA.x, dw0[0], acc0);
        acc1 = fmaf(bfhi(pv0) * mA.x, dw1[0], acc1);
        acc0 = fmaf(bflo(pv1) * mA.y, dw0[1], acc0);
        acc1 = fmaf(bfhi(pv1) * mA.y, dw1[1], acc1);
        acc0 = fmaf(bflo(pv2) * mA.z, dw0[2], acc0);
        acc1 = fmaf(bfhi(pv2) * mA.z, dw1[2], acc1);
        acc0 = fmaf(bflo(pv3) * mA.w, dw0[3], acc0);
        acc1 = fmaf(bfhi(pv3) * mA.w, dw1[3], acc1);
        acc0 = fmaf(bflo(pv4) * mB.x, dw0[4], acc0);
        acc1 = fmaf(bfhi(pv4) * mB.x, dw1[4], acc1);
        acc0 = fmaf(bflo(pv5) * mB.y, dw0[5], acc0);
        acc1 = fmaf(bfhi(pv5) * mB.y, dw1[5], acc1);
        acc0 = fmaf(bflo(pv6) * mB.z, dw0[6], acc0);
        acc1 = fmaf(bfhi(pv6) * mB.z, dw1[6], acc1);
        acc0 = fmaf(bflo(pv7) * mB.w, dw0[7], acc0);
        acc1 = fmaf(bfhi(pv7) * mB.w, dw1[7], acc1);
        acc0 = fmaf(bflo(pv8) * m8,   dw0[8], acc0);
        acc1 = fmaf(bfhi(pv8) * m8,   dw1[8], acc1);

        yslab[(long)(base_l + l) * 8 + d] = pack2(acc0, acc1);
        sum0 += acc0; sum1 += acc1;
        sq0 = fmaf(acc0, acc0, sq0);
        sq1 = fmaf(acc1, acc1, sq1);
    }

    // ---- block reduction: sum over (wave, lsub) for each (quantity, d) ----
    __syncthreads();                 // lcks/mult dead
    red[0 * 256 + tid] = sum0;
    red[1 * 256 + tid] = sum1;
    red[2 * 256 + tid] = sq0;
    red[3 * 256 + tid] = sq1;
    __syncthreads();

    const int grp = tid >> 6;        // quantity
    const int i = tid & 63;
    float t = red[grp * 256 + i] + red[grp * 256 + 64 + i] +
              red[grp * 256 + 128 + i] + red[grp * 256 + 192 + i];
    float* red2 = red + 1024;
    red2[grp * 64 + i] = t;
    __syncthreads();

    if (tid < 32) {                  // q = tid>>3 quantity, dd = tid&7
        const int q = tid >> 3, dd = tid & 7;
        float s = 0.f;
        #pragma unroll
        for (int j = 0; j < 8; ++j) s += red2[q * 64 + j * 8 + dd];
        float* dst = (q & 2) ? gsq : gsum;
        atomicAdd(&dst[g * 16 + 2 * dd + (q & 1)], s);
    }
}

// ---------------------------------------------------------------------------
// Kernel C: BN finalize + SiLU + transpose ybuf slabs (bf16) -> out[q][c][r]
// (fp32) via LDS tile [c][r].
// Grid: Q*(M*M/128) = 1280 blocks, 256 threads.
// ---------------------------------------------------------------------------
__global__ __launch_bounds__(256) void finalize_kernel(
    const unsigned int* __restrict__ ybuf,     // [8][L][8]
    const float* __restrict__ gsum, const float* __restrict__ gsq,
    const float* __restrict__ gamma, const float* __restrict__ beta,
    float* __restrict__ out)                   // [Q*NCH][16384]
{
    __shared__ unsigned short tile[128 * 130];  // [c][r], stride 130
    const int tid = threadIdx.x;
    const int lane = tid & 63;
    const int wave = tid >> 6;
    const int q = blockIdx.x >> 7;
    const int r0 = (blockIdx.x & 127) * 128;
    const int gg = lane >> 3, dd = lane & 7;
    const int c0 = gg * 16 + 2 * dd, c1 = c0 + 1;

    const long lbase = (long)q * 16384 + r0;
    #pragma unroll 8
    for (int it = 0; it < 32; ++it) {
        int r = wave + (it << 2);
        unsigned int u = __builtin_nontemporal_load(
            &ybuf[((long)gg * L_TOTAL + lbase + r) * 8 + dd]);
        tile[c0 * 130 + r] = (unsigned short)(u & 0xffffu);
        tile[c1 * 130 + r] = (unsigned short)(u >> 16);
    }
    __syncthreads();

    const float invN = 1.0f / (float)L_TOTAL;
    #pragma unroll 4
    for (int it = 0; it < 32; ++it) {
        int c = wave + (it << 2);
        float m = gsum[c] * invN;
        float var = gsq[c] * invN - m * m;
        float sc = gamma[c] * rsqrtf(var + 1e-5f);
        float sh = beta[c] - m * sc;
        unsigned int d = *reinterpret_cast<const unsigned int*>(&tile[c * 130 + 2 * lane]);
        float z0 = fmaf(bflo(d), sc, sh);
        float z1 = fmaf(bfhi(d), sc, sh);
        f32x2 v;
        v.x = z0 / (1.0f + __expf(-z0));
        v.y = z1 / (1.0f + __expf(-z1));
        *(f32x2*)&out[((long)(q * NCH + c) << 14) + r0 + 2 * lane] = v;
    }
}

extern "C" void kernel_launch(void* const* d_in, const int* in_sizes, int n_in,
                              void* d_out, int out_size, void* d_ws, size_t ws_size,
                              hipStream_t stream) {
    const f32x2* x_f2  = (const f32x2*)d_in[0];
    const int* cks     = (const int*)d_in[1];
    const float* aw    = (const float*)d_in[2];
    const float* ab    = (const float*)d_in[3];
    const float* dw    = (const float*)d_in[4];
    const float* db    = (const float*)d_in[5];
    const float* gm    = (const float*)d_in[6];
    const float* bt    = (const float*)d_in[7];

    char* ws = (char*)d_ws;
    unsigned int* xT   = (unsigned int*)ws;                  // 33,554,432 B
    float2* meanmaxP   = (float2*)(ws + 33554432);           // 1,048,576 B
    unsigned int* ybuf = (unsigned int*)(ws + 34603008);     // 41,943,040 B
    float* multg       = (float*)(ws + 76546048);            // 7,864,320 B
    float* gsum        = (float*)(ws + 84410368);            // 512 B
    float* gsq         = gsum + NCH;                         // 512 B

    hipMemsetAsync(gsum, 0, 2 * NCH * sizeof(float), stream);

    transpose_x_kernel<<<HW / 128, 256, 0, stream>>>(x_f2, xT, meanmaxP);
    mult_kernel<<<L_TOTAL / 64, 256, 0, stream>>>(meanmaxP, cks, aw, ab, multg);
    gather_kernel<<<(L_TOTAL / LPB) * NGRP, 256, 0, stream>>>(
        xT, cks, multg, dw, db, ybuf, gsum, gsq);
    finalize_kernel<<<1280, 256, 0, stream>>>(
        ybuf, gsum, gsq, gm, bt, (float*)d_out);
}

// Round 4
// 300.286 us; speedup vs baseline: 1.1561x; 1.0104x over previous
//
#include <hip/hip_runtime.h>
#include <hip/hip_bf16.h>

#define HW 131072      // h*w
#define NCH 128        // channels
#define KS 9
#define L_TOTAL 163840 // Q*M*M
#define NGRP 8         // channel groups == XCDs
#define LPB 128        // l's per block in gather kernel

typedef float        f32x2 __attribute__((ext_vector_type(2)));
typedef float        f32x4 __attribute__((ext_vector_type(4)));
typedef unsigned int u32x2 __attribute__((ext_vector_type(2)));
typedef unsigned int u32x4 __attribute__((ext_vector_type(4)));

static __device__ __forceinline__ float bflo(unsigned int p) { return __uint_as_float(p << 16); }
static __device__ __forceinline__ float bfhi(unsigned int p) { return __uint_as_float(p & 0xffff0000u); }
static __device__ __forceinline__ unsigned short f2bf(float f) {
    unsigned int x = __float_as_uint(f);
    return (unsigned short)((x + 0x7fffu + ((x >> 16) & 1u)) >> 16);  // RNE
}
static __device__ __forceinline__ unsigned int pack2(float a, float b) {
    return (unsigned int)f2bf(a) | ((unsigned int)f2bf(b) << 16);
}

// ---------------------------------------------------------------------------
// Kernel A: transpose x[c][p] (fp32) -> xT slabs: [g][p][8 dwords] where
// slab g holds channels [16g, 16g+16) as bf16 pairs (32 B per row = 4 MB
// per slab = one XCD L2). Also per-p channel mean/max.  (unchanged)
// Grid: HW/128 = 1024 blocks, 256 threads.
// ---------------------------------------------------------------------------
__global__ __launch_bounds__(256) void transpose_x_kernel(
    const f32x2* __restrict__ xf,         // x: [NCH][HW/2] float2 along p
    unsigned int* __restrict__ xT,        // [8][HW][8] dword slabs
    float2* __restrict__ meanmaxP)        // [HW] (mean, max) over channels
{
    __shared__ unsigned short tile[128 * 128];  // [p][col'], rotate swizzle
    __shared__ float ps[4][128];
    __shared__ float pm[4][128];
    const int tid = threadIdx.x;
    const int lane = tid & 63;
    const int wave = tid >> 6;
    const int p0 = blockIdx.x * 128;
    const int pa = 2 * lane, pb = 2 * lane + 1;

    float s0 = 0.f, s1 = 0.f;
    float m0 = -3.4e38f, m1 = -3.4e38f;
    #pragma unroll 8
    for (int it = 0; it < 32; ++it) {
        int c = wave + (it << 2);
        f32x2 v = __builtin_nontemporal_load(&xf[(long)c * (HW / 2) + (p0 >> 1) + lane]);
        tile[pa * 128 + ((c + 2 * pa) & 127)] = f2bf(v.x);
        tile[pb * 128 + ((c + 2 * pb) & 127)] = f2bf(v.y);
        s0 += v.x; s1 += v.y;
        m0 = fmaxf(m0, v.x); m1 = fmaxf(m1, v.y);
    }
    ps[wave][pa] = s0; ps[wave][pb] = s1;
    pm[wave][pa] = m0; pm[wave][pb] = m1;
    __syncthreads();

    #pragma unroll 8
    for (int it = 0; it < 32; ++it) {
        int p = wave + (it << 2);
        int colr = (2 * lane + 2 * p) & 127;          // even -> dword aligned
        unsigned int d = *reinterpret_cast<const unsigned int*>(&tile[p * 128 + colr]);
        // dword holds channels (2*lane, 2*lane+1) -> slab lane>>3, sub lane&7
        xT[((long)(lane >> 3) * HW + (p0 + p)) * 8 + (lane & 7)] = d;
    }
    if (tid < 128) {
        float s = ps[0][tid] + ps[1][tid] + ps[2][tid] + ps[3][tid];
        float m = fmaxf(fmaxf(pm[0][tid], pm[1][tid]), fmaxf(pm[2][tid], pm[3][tid]));
        meanmaxP[p0 + tid] = make_float2(s * 0.0078125f, m);
    }
}

// ---------------------------------------------------------------------------
// Kernel B1: attention multipliers -> PACKED records.
// rec[l][k] = idx (17 bits) | round(sigmoid(logit)*32768) << 17  (15 bits).
// Quantization err 1.5e-5 on mult in [1,2] -- negligible vs bf16 x (0.4%).
// One stream for the gather kernel instead of two (cks+mult).
// Grid: L_TOTAL/64 = 2560 blocks, 256 threads.
// ---------------------------------------------------------------------------
__global__ __launch_bounds__(256) void mult_kernel(
    const float2* __restrict__ meanmaxP,       // [HW]
    const int* __restrict__ cks,               // [L][9]
    const float* __restrict__ att_w,           // [9][2][9]
    const float* __restrict__ att_b,           // [9]
    unsigned int* __restrict__ rec)            // [L][12] packed (0..8 used)
{
    __shared__ float attw[162];
    __shared__ float attb[12];
    __shared__ int lcks[64 * 12];
    const int tid = threadIdx.x;
    const int base_l = blockIdx.x * 64;

    if (tid < 162) attw[tid] = att_w[tid];
    if (tid < KS) attb[tid] = att_b[tid];
    for (int j = tid; j < 64 * KS; j += 256) {
        const int lj = j / KS;
        lcks[lj * 12 + (j - lj * KS)] = cks[(long)base_l * KS + j];
    }
    __syncthreads();

    const int l_local = tid >> 2;
    const int sub = tid & 3;
    if (sub < 3) {
        float mean[KS], mx[KS];
        #pragma unroll
        for (int k = 0; k < KS; ++k) {
            float2 mm = meanmaxP[lcks[l_local * 12 + k]];
            mean[k] = mm.x; mx[k] = mm.y;
        }
        #pragma unroll
        for (int oo = 0; oo < 3; ++oo) {
            int o = sub * 3 + oo;
            float logit = attb[o];
            #pragma unroll
            for (int k = 0; k < KS; ++k) {
                logit = fmaf(mean[k], attw[o * 18 + k], logit);
                logit = fmaf(mx[k],   attw[o * 18 + 9 + k], logit);
            }
            float sig = 1.0f / (1.0f + __expf(-logit));
            unsigned int u = (unsigned int)(sig * 32768.0f + 0.5f);
            if (u > 32767u) u = 32767u;
            rec[(long)(base_l + l_local) * 12 + o] =
                (unsigned int)lcks[l_local * 12 + o] | (u << 17);
        }
    }
}

// ---------------------------------------------------------------------------
// Kernel B2: XCD-sliced gather + depthwise, instruction-minimized.
// Lane layout: qt = lane&3 owns 4 channels (8 bytes of the 32-B row),
// lq = lane>>2 picks the l. One wave instruction gathers one k-row for
// 16 l's (uint2/lane) -- half the VMEM instructions of the dword version.
// rec rows loaded directly per-lane (3x b128/b32, 4 lanes/line, coalesced);
// no LDS staging, no mid-loop barriers -> waves fully independent.
// Channel-pair math via f32x2 -> v_pk_mul/v_pk_fma.
// Grid: (L_TOTAL/LPB)*8 = 10240 blocks, 256 threads.
// ---------------------------------------------------------------------------
__global__ __launch_bounds__(256, 4) void gather_kernel(
    const unsigned int* __restrict__ xT,       // [8][HW][8]
    const unsigned int* __restrict__ rec,      // [L][12] packed
    const float* __restrict__ depth_w,         // [128][9]
    const float* __restrict__ depth_b,         // [128]
    unsigned int* __restrict__ ybuf,           // [8][L][8] bf16-pair slabs
    float* __restrict__ gsum, float* __restrict__ gsq)
{
    __shared__ float dwl[KS][16];   // [k][ch-in-group]
    __shared__ float dbl[16];
    __shared__ float redx[4][4][8]; // [wave][qt][quantity]

    const int tid  = threadIdx.x;
    const int lane = tid & 63;
    const int wave = tid >> 6;
    const int g      = blockIdx.x & 7;
    const int base_l = (blockIdx.x >> 3) * LPB;
    const int qt = lane & 3;        // 8-byte chunk of 32-B row
    const int lq = lane >> 2;       // l within batch of 16

    if (tid < 144) {
        int k = tid >> 4, ch = tid & 15;
        dwl[k][ch] = depth_w[(g * 16 + ch) * KS + k];
    }
    if (tid < 16) dbl[tid] = depth_b[g * 16 + tid];
    __syncthreads();

    f32x2 dw[KS][2];
    #pragma unroll
    for (int k = 0; k < KS; ++k) {
        f32x4 t = *(const f32x4*)&dwl[k][qt * 4];
        dw[k][0].x = t.x; dw[k][0].y = t.y;
        dw[k][1].x = t.z; dw[k][1].y = t.w;
    }
    f32x2 db01, db23;
    {
        f32x4 t = *(const f32x4*)&dbl[qt * 4];
        db01.x = t.x; db01.y = t.y; db23.x = t.z; db23.y = t.w;
    }

    const unsigned int* slab  = xT   + ((size_t)g << 20);         // g*HW*8
    unsigned int*       yslab = ybuf + (size_t)g * (L_TOTAL * 8);

    f32x2 sum01 = {0.f, 0.f}, sum23 = {0.f, 0.f};
    f32x2 sq01  = {0.f, 0.f}, sq23  = {0.f, 0.f};

    #pragma unroll
    for (int b = 0; b < 2; ++b) {
        const int lloc = wave * 32 + b * 16 + lq;
        const unsigned int* rp = rec + (size_t)(base_l + lloc) * 12;
        const u32x4 r0 = __builtin_nontemporal_load((const u32x4*)rp);
        const u32x4 r1 = __builtin_nontemporal_load((const u32x4*)(rp + 4));
        const unsigned int r8 = __builtin_nontemporal_load(rp + 8);
        const unsigned int rr[KS] = {r0.x, r0.y, r0.z, r0.w,
                                     r1.x, r1.y, r1.z, r1.w, r8};

        u32x2 pv[KS];
        #pragma unroll
        for (int k = 0; k < KS; ++k)
            pv[k] = *(const u32x2*)(slab + ((rr[k] & 0x1FFFFu) << 3) + (qt << 1));

        f32x2 acc01 = db01, acc23 = db23;
        #pragma unroll
        for (int k = 0; k < KS; ++k) {
            const float mk = fmaf((float)(rr[k] >> 17), 3.0517578125e-5f, 1.0f);
            f32x2 mk2; mk2.x = mk; mk2.y = mk;
            f32x2 xa; xa.x = bflo(pv[k].x); xa.y = bfhi(pv[k].x);
            f32x2 xb; xb.x = bflo(pv[k].y); xb.y = bfhi(pv[k].y);
            acc01 = __builtin_elementwise_fma(xa * mk2, dw[k][0], acc01);
            acc23 = __builtin_elementwise_fma(xb * mk2, dw[k][1], acc23);
        }

        u32x2 o;
        o.x = pack2(acc01.x, acc01.y);
        o.y = pack2(acc23.x, acc23.y);
        *(u32x2*)(yslab + (size_t)(base_l + lloc) * 8 + (qt << 1)) = o;

        sum01 += acc01; sum23 += acc23;
        sq01 = __builtin_elementwise_fma(acc01, acc01, sq01);
        sq23 = __builtin_elementwise_fma(acc23, acc23, sq23);
    }

    // ---- reduction over lq (lane bits 2..5) via butterfly shuffles ----
    #pragma unroll
    for (int s = 4; s <= 32; s <<= 1) {
        sum01.x += __shfl_xor(sum01.x, s);
        sum01.y += __shfl_xor(sum01.y, s);
        sum23.x += __shfl_xor(sum23.x, s);
        sum23.y += __shfl_xor(sum23.y, s);
        sq01.x  += __shfl_xor(sq01.x,  s);
        sq01.y  += __shfl_xor(sq01.y,  s);
        sq23.x  += __shfl_xor(sq23.x,  s);
        sq23.y  += __shfl_xor(sq23.y,  s);
    }
    if (lane < 4) {
        float* rw = &redx[wave][lane][0];
        rw[0] = sum01.x; rw[1] = sum01.y; rw[2] = sum23.x; rw[3] = sum23.y;
        rw[4] = sq01.x;  rw[5] = sq01.y;  rw[6] = sq23.x;  rw[7] = sq23.y;
    }
    __syncthreads();
    if (tid < 32) {
        const int q = tid >> 2, qq = tid & 3;   // q: quantity, qq: qt
        float s = redx[0][qq][q] + redx[1][qq][q] + redx[2][qq][q] + redx[3][qq][q];
        const int ch = g * 16 + qq * 4 + (q & 3);
        float* dst = (q >= 4) ? gsq : gsum;
        atomicAdd(&dst[ch], s);
    }
}

// ---------------------------------------------------------------------------
// Kernel C: BN finalize + SiLU + transpose ybuf slabs (bf16) -> out[q][c][r]
// (fp32) via LDS tile [c][r].  (unchanged)
// Grid: Q*(M*M/128) = 1280 blocks, 256 threads.
// ---------------------------------------------------------------------------
__global__ __launch_bounds__(256) void finalize_kernel(
    const unsigned int* __restrict__ ybuf,     // [8][L][8]
    const float* __restrict__ gsum, const float* __restrict__ gsq,
    const float* __restrict__ gamma, const float* __restrict__ beta,
    float* __restrict__ out)                   // [Q*NCH][16384]
{
    __shared__ unsigned short tile[128 * 130];  // [c][r], stride 130
    const int tid = threadIdx.x;
    const int lane = tid & 63;
    const int wave = tid >> 6;
    const int q = blockIdx.x >> 7;
    const int r0 = (blockIdx.x & 127) * 128;
    const int gg = lane >> 3, dd = lane & 7;
    const int c0 = gg * 16 + 2 * dd, c1 = c0 + 1;

    const long lbase = (long)q * 16384 + r0;
    #pragma unroll 8
    for (int it = 0; it < 32; ++it) {
        int r = wave + (it << 2);
        unsigned int u = __builtin_nontemporal_load(
            &ybuf[((long)gg * L_TOTAL + lbase + r) * 8 + dd]);
        tile[c0 * 130 + r] = (unsigned short)(u & 0xffffu);
        tile[c1 * 130 + r] = (unsigned short)(u >> 16);
    }
    __syncthreads();

    const float invN = 1.0f / (float)L_TOTAL;
    #pragma unroll 4
    for (int it = 0; it < 32; ++it) {
        int c = wave + (it << 2);
        float m = gsum[c] * invN;
        float var = gsq[c] * invN - m * m;
        float sc = gamma[c] * rsqrtf(var + 1e-5f);
        float sh = beta[c] - m * sc;
        unsigned int d = *reinterpret_cast<const unsigned int*>(&tile[c * 130 + 2 * lane]);
        float z0 = fmaf(bflo(d), sc, sh);
        float z1 = fmaf(bfhi(d), sc, sh);
        f32x2 v;
        v.x = z0 / (1.0f + __expf(-z0));
        v.y = z1 / (1.0f + __expf(-z1));
        *(f32x2*)&out[((long)(q * NCH + c) << 14) + r0 + 2 * lane] = v;
    }
}

extern "C" void kernel_launch(void* const* d_in, const int* in_sizes, int n_in,
                              void* d_out, int out_size, void* d_ws, size_t ws_size,
                              hipStream_t stream) {
    const f32x2* x_f2  = (const f32x2*)d_in[0];
    const int* cks     = (const int*)d_in[1];
    const float* aw    = (const float*)d_in[2];
    const float* ab    = (const float*)d_in[3];
    const float* dw    = (const float*)d_in[4];
    const float* db    = (const float*)d_in[5];
    const float* gm    = (const float*)d_in[6];
    const float* bt    = (const float*)d_in[7];

    char* ws = (char*)d_ws;
    unsigned int* xT   = (unsigned int*)ws;                  // 33,554,432 B
    float2* meanmaxP   = (float2*)(ws + 33554432);           // 1,048,576 B
    unsigned int* ybuf = (unsigned int*)(ws + 34603008);     // 41,943,040 B
    unsigned int* rec  = (unsigned int*)(ws + 76546048);     // 7,864,320 B
    float* gsum        = (float*)(ws + 84410368);            // 512 B
    float* gsq         = gsum + NCH;                         // 512 B

    hipMemsetAsync(gsum, 0, 2 * NCH * sizeof(float), stream);

    transpose_x_kernel<<<HW / 128, 256, 0, stream>>>(x_f2, xT, meanmaxP);
    mult_kernel<<<L_TOTAL / 64, 256, 0, stream>>>(meanmaxP, cks, aw, ab, rec);
    gather_kernel<<<(L_TOTAL / LPB) * NGRP, 256, 0, stream>>>(
        xT, rec, dw, db, ybuf, gsum, gsq);
    finalize_kernel<<<1280, 256, 0, stream>>>(
        ybuf, gsum, gsq, gm, bt, (float*)d_out);
}